// Round 16
// baseline (313.751 us; speedup 1.0000x reference)
//
#include <hip/hip_runtime.h>

#define B_   2
#define D_   32
#define H_   256
#define W_   256
#define N_   150000
#define CIN  16
#define CMID 32
#define COUT 64
#define DO_  16
#define HO_  128
#define WO_  128
#define M_   (B_*DO_*HO_*WO_)   /* 524288 */
#define EPSf 1e-5f
#define NB_DOWN 8192             /* k_down blocks; %8==0, 64 voxels per block */
#define NREP 64                  /* stats slabs (atomic de-contention) */

typedef _Float16 h2 __attribute__((ext_vector_type(2)));
__device__ inline h2 as_h2(unsigned u) { union { unsigned u; h2 h; } x; x.u = u; return x.h; }

#if defined(__has_builtin) && __has_builtin(__builtin_amdgcn_fdot2)
__device__ inline float dot2(unsigned f, unsigned w, float acc) {
    return __builtin_amdgcn_fdot2(as_h2(f), as_h2(w), acc, false);
}
#else
__device__ inline float dot2(unsigned f, unsigned w, float acc) {
    const h2 a = as_h2(f), b = as_h2(w);
    return fmaf((float)a.x, (float)b.x, fmaf((float)a.y, (float)b.y, acc));
}
#endif

#if defined(__has_builtin) && __has_builtin(__builtin_amdgcn_readlane)
#define RDLANE(v, l) __builtin_amdgcn_readlane((v), (l))
#else
#define RDLANE(v, l) __shfl((v), (l), 64)
#endif

// pack two floats into one dword of fp16 (RNE via _Float16 cast)
__device__ inline unsigned hpk(float a, float b) {
    union { _Float16 h[2]; unsigned u; } x;
    x.h[0] = (_Float16)a; x.h[1] = (_Float16)b; return x.u;
}

// ---------------- grid scatter ----------------
__global__ __launch_bounds__(256) void k_scatter(const int* __restrict__ coords,
                                                 int* __restrict__ grid) {
    int i = blockIdx.x * 256 + threadIdx.x;
    if (i >= N_) return;
    const int4 c = *(const int4*)(coords + 4 * (size_t)i);
    grid[((c.x * D_ + c.y) * H_ + c.z) * W_ + c.w] = i;
}

// ---------------- weight transpose+pack to fp16 pairs ----------------
__global__ __launch_bounds__(256) void k_twisth(const float* __restrict__ W1,
                                                const float* __restrict__ W2,
                                                const float* __restrict__ W3,
                                                uint4* __restrict__ Wh1,
                                                uint4* __restrict__ Wh2,
                                                uint4* __restrict__ Wh3) {
    const int t = blockIdx.x * 256 + threadIdx.x;
    if (t < 1728) {
        const int ki = t / 64, r = t % 64, half = r >> 5, sub = r & 31;
        const float* base = W1 + ki * 512 + (half * 8) * 32 + sub;
        uint4 o;
        o.x = hpk(base[0],   base[32]);
        o.y = hpk(base[64],  base[96]);
        o.z = hpk(base[128], base[160]);
        o.w = hpk(base[192], base[224]);
        Wh1[(ki * 2 + half) * 32 + sub] = o;
    } else if (t < 1728 + 3456) {
        const int u = t - 1728;
        const int ki = u / 128, r = u % 128, qh = r >> 5, sub = r & 31;
        const int half = qh >> 1, q = qh & 1;
        const float* base = W2 + ki * 1024 + (half * 16 + q * 8) * 32 + sub;
        uint4 o;
        o.x = hpk(base[0],   base[32]);
        o.y = hpk(base[64],  base[96]);
        o.z = hpk(base[128], base[160]);
        o.w = hpk(base[192], base[224]);
        Wh2[((ki * 2 + half) * 2 + q) * 32 + sub] = o;
    } else if (t < 1728 + 3456 + 6912) {
        const int u = t - 5184;
        const int ki = u / 256, r = u % 256, q = r >> 6, lane = r & 63;
        const float* base = W3 + ki * 2048 + (q * 8) * 64 + lane;
        uint4 o;
        o.x = hpk(base[0],   base[64]);
        o.y = hpk(base[128], base[192]);
        o.z = hpk(base[256], base[320]);
        o.w = hpk(base[384], base[448]);
        Wh3[(ki * 4 + q) * 64 + lane] = o;
    }
}

// ---------------- feats fp32 -> fp16 pack ----------------
__global__ __launch_bounds__(256) void k_feat16(const float* __restrict__ F,
                                                unsigned* __restrict__ F16) {
    const int i = blockIdx.x * 256 + threadIdx.x;   // one float4 -> uint2
    if (i >= N_ * CIN / 4) return;
    const float4 v = ((const float4*)F)[i];
    uint2 o; o.x = hpk(v.x, v.y); o.y = hpk(v.z, v.w);
    ((uint2*)F16)[i] = o;
}

// ------- submanifold conv: 4 points/wave, branched 4-chain, fused stats -----
template <int CI>
__global__ __launch_bounds__(256) void k_subm(const unsigned* __restrict__ X16,
                                              const int* __restrict__ coords,
                                              const int* __restrict__ grid,
                                              const uint4* __restrict__ Wh,
                                              const float* __restrict__ bias,
                                              _Float16* __restrict__ Yp,
                                              float* __restrict__ slab0) {
    constexpr int NQ = CI / 16;   // uint4 loads per tap per lane (1 or 2)
    const int wid  = (blockIdx.x * 256 + threadIdx.x) >> 6;
    const int lane = threadIdx.x & 63;
    const int sub  = lane & 31;
    const int half = lane >> 5;
    const int i0   = wid * 4;

    int nidx01 = -1, nidx23 = -1;
    {
        const int4 cc = *(const int4*)(coords + 4 * (size_t)(i0 + half));
        if (sub < 27) {
            const int nz = cc.y + sub / 9 - 1;
            const int ny = cc.z + (sub / 3) % 3 - 1;
            const int nx = cc.w + sub % 3 - 1;
            if ((unsigned)nz < (unsigned)D_ && (unsigned)ny < (unsigned)H_ &&
                (unsigned)nx < (unsigned)W_)
                nidx01 = grid[((cc.x * D_ + nz) * H_ + ny) * W_ + nx];
        }
    }
    {
        const int4 cc = *(const int4*)(coords + 4 * (size_t)(i0 + 2 + half));
        if (sub < 27) {
            const int nz = cc.y + sub / 9 - 1;
            const int ny = cc.z + (sub / 3) % 3 - 1;
            const int nx = cc.w + sub % 3 - 1;
            if ((unsigned)nz < (unsigned)D_ && (unsigned)ny < (unsigned)H_ &&
                (unsigned)nx < (unsigned)W_)
                nidx23 = grid[((cc.x * D_ + nz) * H_ + ny) * W_ + nx];
        }
    }
    const unsigned long long a01 = __ballot(nidx01 >= 0);
    const unsigned long long a23 = __ballot(nidx23 >= 0);
    unsigned m0 = (unsigned)a01 & 0x7FFFFFFu;
    unsigned m1 = (unsigned)(a01 >> 32) & 0x7FFFFFFu;
    unsigned m2 = (unsigned)a23 & 0x7FFFFFFu;
    unsigned m3 = (unsigned)(a23 >> 32) & 0x7FFFFFFu;

    float4 ac0 = {0.f, 0.f, 0.f, 0.f}, ac1 = {0.f, 0.f, 0.f, 0.f};
    float4 ac2 = {0.f, 0.f, 0.f, 0.f}, ac3 = {0.f, 0.f, 0.f, 0.f};

    auto tap = [&](int ki, int ni, float4& ac) {
        const uint4* __restrict__ f =
            (const uint4*)(X16 + (size_t)ni * (CI / 2) + half * (CI / 4));
        const uint4* __restrict__ wb = Wh + ((size_t)(ki * 2 + half)) * NQ * 32 + sub;
#pragma unroll
        for (int q = 0; q < NQ; ++q) {
            const uint4 fu = f[q];
            const uint4 wu = wb[q * 32];
            ac.x = dot2(fu.x, wu.x, ac.x);
            ac.y = dot2(fu.y, wu.y, ac.y);
            ac.z = dot2(fu.z, wu.z, ac.z);
            ac.w = dot2(fu.w, wu.w, ac.w);
        }
    };

    while (m0 | m1 | m2 | m3) {
        if (m0) { const int ki = __builtin_ctz(m0); m0 &= m0 - 1;
                  tap(ki, __shfl(nidx01, ki, 64),      ac0); }
        if (m1) { const int ki = __builtin_ctz(m1); m1 &= m1 - 1;
                  tap(ki, __shfl(nidx01, ki + 32, 64), ac1); }
        if (m2) { const int ki = __builtin_ctz(m2); m2 &= m2 - 1;
                  tap(ki, __shfl(nidx23, ki, 64),      ac2); }
        if (m3) { const int ki = __builtin_ctz(m3); m3 &= m3 - 1;
                  tap(ki, __shfl(nidx23, ki + 32, 64), ac3); }
    }

    float s0 = (ac0.x + ac0.y) + (ac0.z + ac0.w);
    float s1 = (ac1.x + ac1.y) + (ac1.z + ac1.w);
    float s2v = (ac2.x + ac2.y) + (ac2.z + ac2.w);
    float s3 = (ac3.x + ac3.y) + (ac3.z + ac3.w);
    s0 += __shfl_xor(s0, 32, 64);
    s1 += __shfl_xor(s1, 32, 64);
    s2v += __shfl_xor(s2v, 32, 64);
    s3 += __shfl_xor(s3, 32, 64);
    const float bv  = bias[sub];
    const float o01 = (half ? s1 : s0) + bv;   // point i0+half
    const float o23 = (half ? s3 : s2v) + bv;  // point i0+2+half
    Yp[(size_t)(i0 + half) * 32 + sub]     = (_Float16)o01;
    Yp[(size_t)(i0 + 2 + half) * 32 + sub] = (_Float16)o23;

    // fused BN stats into NREP slabs
    __shared__ float sd[256];
    const int tid = threadIdx.x;
    float* __restrict__ slab = slab0 + (size_t)(blockIdx.x & (NREP - 1)) * 64;
    sd[tid] = o01 + o23;
    __syncthreads();
    if (tid < 32) {
        float t = 0.f;
#pragma unroll
        for (int k = 0; k < 8; ++k) t += sd[tid + 32 * k];
        atomicAdd(slab + tid, t);
    }
    __syncthreads();
    sd[tid] = o01 * o01 + o23 * o23;
    __syncthreads();
    if (tid < 32) {
        float t = 0.f;
#pragma unroll
        for (int k = 0; k < 8; ++k) t += sd[tid + 32 * k];
        atomicAdd(slab + 32 + tid, t);
    }
}

// ------ strided down conv: lane-resident tap stream + depth-4 prefetch ------
// All ~15 taps of a wave's 16 voxels are flattened (via ds_permute) into a
// voxel-ordered stream living in lanes 0..ntap-1. The main loop is one basic
// block: extraction = v_readlane (no mem counter); feature row + weights are
// prefetched 4 taps ahead as VECTOR loads (in-order vmcnt -> partial waits),
// issued in exact consumption order.
__global__ __launch_bounds__(256) void k_down(const unsigned* __restrict__ X16,
                                              const int* __restrict__ grid,
                                              const uint4* __restrict__ Wh3,
                                              const float* __restrict__ bias,
                                              _Float16* __restrict__ Yh,
                                              unsigned char* __restrict__ mask,
                                              float* __restrict__ slab0,
                                              int* __restrict__ nacts) {
    const int b    = blockIdx.x;
    const int swz  = (b & 7) * (NB_DOWN / 8) + (b >> 3);
    const int tid  = threadIdx.x;
    const int wv   = tid >> 6;
    const int lane = tid & 63;
    const int sub  = lane & 31;
    const int half = lane >> 5;

    const int vox0 = swz * 64;
    const int ox0  = vox0 & 127;      // 0 or 64
    int t0 = vox0 >> 7;
    const int oy = t0 & 127; t0 >>= 7;
    const int oz = t0 & 15;
    const int bb = t0 >> 4;

    __shared__ int   gl[9][132];
    __shared__ float sd[256];
    __shared__ int   scnt[4];

    const int gx0 = 2 * ox0 - 1;
#pragma unroll
    for (int r = 0; r < 9; ++r) {
        const int z = 2 * oz - 1 + r / 3;
        const int y = 2 * oy - 1 + r % 3;
        if (tid < 132) {
            const int xo = tid;
            const int x  = gx0 + xo;
            int v = -1;
            if ((unsigned)z < (unsigned)D_ && (unsigned)y < (unsigned)H_ &&
                (unsigned)x < (unsigned)W_ && xo < 129)
                v = grid[((bb * D_ + z) * H_ + y) * W_ + x];
            gl[r][xo] = v;
        }
    }
    __syncthreads();

    const int dz = sub / 9, dy = (sub / 3) % 3, dx = sub % 3;
    const int row = (sub < 27) ? dz * 3 + dy : 0;
    const int wbase = wv * 16;        // wave's 16 local voxels

    // ---- probe all 16 voxels (8 pairs) ----
    int nP[8];
    unsigned long long aP[8];
#pragma unroll
    for (int p = 0; p < 8; ++p) {
        const int vl = wbase + 2 * p + half;
        nP[p] = (sub < 27) ? gl[row][2 * vl + dx] : -1;
        aP[p] = __ballot(nP[p] >= 0);
    }

    int pcA[16];
#pragma unroll
    for (int p = 0; p < 8; ++p) {
        pcA[2 * p]     = __popcll(aP[p] & 0x7FFFFFFull);
        pcA[2 * p + 1] = __popcll((aP[p] >> 32) & 0x7FFFFFFull);
    }
    int baseA[16]; int ntap = 0;
#pragma unroll
    for (int v = 0; v < 16; ++v) { baseA[v] = ntap; ntap += pcA[v]; }

    const float bv = bias[lane];
    float s = 0.f, s2 = 0.f;
    int cnt = 0;

    // mask writes + zero rows for empty voxels
#pragma unroll
    for (int v = 0; v < 16; ++v) {
        if (pcA[v] == 0)
            Yh[(size_t)(vox0 + wbase + v) * COUT + lane] = (_Float16)0.f;
        if (lane == 0) {
            const int a = pcA[v] ? 1 : 0;
            mask[vox0 + wbase + v] = (unsigned char)a;
            cnt += a;
        }
    }

    if (ntap <= 62) {
        // ---- build lane-resident stream: lane 'slot' gets (meta, ni) ----
        int metaV = 0, niV = 0;
#pragma unroll
        for (int p = 0; p < 8; ++p) {
            const unsigned mA = (unsigned)(aP[p] & 0x7FFFFFFull);
            const unsigned mB = (unsigned)((aP[p] >> 32) & 0x7FFFFFFull);
            const unsigned myM = half ? mB : mA;
            const int  sb    = sub & 31;
            const bool valid = (sub < 27) && ((myM >> sb) & 1u);
            const unsigned below = myM & ((1u << sb) - 1u);
            const int slot = (half ? baseA[2 * p + 1] : baseA[2 * p]) + __popc(below);
            const int isLast = ((myM >> ((sb + 1) & 31)) == 0u) ? 1 : 0;
            const int v = 2 * p + half;
            const int meta = 0x8000 | (v << 5) | sb | (isLast << 9);
            const int addr = (valid ? slot : 63) * 4;
            metaV |= __builtin_amdgcn_ds_permute(addr, valid ? meta : 0);
            niV   |= __builtin_amdgcn_ds_permute(addr, valid ? nP[p] : 0);
        }

        int zv = 0;
        asm volatile("" : "+v"(zv));   // opaque zero: forces VECTOR feature loads

        float4 acc = {0.f, 0.f, 0.f, 0.f};

        auto EXT = [&](int t, int& me, uint4* rf, uint4* rw) {
            me = RDLANE(metaV, t);
            const int ni = RDLANE(niV, t);
            const uint4* fp = (const uint4*)(X16 + (size_t)(ni * 16 + zv));
            const uint4* wp = Wh3 + (size_t)(me & 31) * 256 + lane;
#pragma unroll
            for (int q = 0; q < 4; ++q) { rf[q] = fp[q]; rw[q] = wp[q * 64]; }
        };
        auto CMP = [&](int me, const uint4* rf, const uint4* rw) {
#pragma unroll
            for (int q = 0; q < 4; ++q) {
                acc.x = dot2(rf[q].x, rw[q].x, acc.x);
                acc.y = dot2(rf[q].y, rw[q].y, acc.y);
                acc.z = dot2(rf[q].z, rw[q].z, acc.z);
                acc.w = dot2(rf[q].w, rw[q].w, acc.w);
            }
            if (me & 0x200) {            // last tap of its voxel -> flush
                const int v = (me >> 5) & 15;
                const float o = (acc.x + acc.y) + (acc.z + acc.w) + bv;
                Yh[(size_t)(vox0 + wbase + v) * COUT + lane] = (_Float16)o;
                s += o; s2 += o * o;
                acc.x = 0.f; acc.y = 0.f; acc.z = 0.f; acc.w = 0.f;
            }
        };

        uint4 rf0[4], rw0[4], rf1[4], rw1[4], rf2[4], rw2[4], rf3[4], rw3[4];
        int me0 = 0, me1 = 0, me2 = 0, me3 = 0;
        if (0 < ntap) EXT(0, me0, rf0, rw0);
        if (1 < ntap) EXT(1, me1, rf1, rw1);
        if (2 < ntap) EXT(2, me2, rf2, rw2);
        if (3 < ntap) EXT(3, me3, rf3, rw3);
        for (int t = 0; t < ntap; t += 4) {
            CMP(me0, rf0, rw0);
            if (t + 4 < ntap) EXT(t + 4, me0, rf0, rw0);
            if (t + 1 < ntap) {
                CMP(me1, rf1, rw1);
                if (t + 5 < ntap) EXT(t + 5, me1, rf1, rw1);
            }
            if (t + 2 < ntap) {
                CMP(me2, rf2, rw2);
                if (t + 6 < ntap) EXT(t + 6, me2, rf2, rw2);
            }
            if (t + 3 < ntap) {
                CMP(me3, rf3, rw3);
                if (t + 7 < ntap) EXT(t + 7, me3, rf3, rw3);
            }
        }
    } else {
        // ---- rare fallback (ntap > 62): serial per-voxel ----
#pragma unroll
        for (int v = 0; v < 16; ++v) {
            const unsigned mv = (v & 1)
                ? (unsigned)((aP[v >> 1] >> 32) & 0x7FFFFFFull)
                : (unsigned)(aP[v >> 1] & 0x7FFFFFFull);
            if (mv == 0) continue;
            unsigned m = mv;
            float acc1 = 0.f;
            while (m) {
                const int ki = __builtin_ctz(m); m &= m - 1;
                const int ni = __builtin_amdgcn_readfirstlane(
                                   __shfl(nP[v >> 1], ki + 32 * (v & 1), 64));
                const uint4* __restrict__ fS = (const uint4*)(X16 + (size_t)ni * 16);
                const uint4* __restrict__ wb = Wh3 + (size_t)ki * 256 + lane;
#pragma unroll
                for (int q = 0; q < 4; ++q) {
                    const uint4 fu = fS[q];
                    const uint4 wu = wb[q * 64];
                    acc1 = dot2(fu.x, wu.x, acc1);
                    acc1 = dot2(fu.y, wu.y, acc1);
                    acc1 = dot2(fu.z, wu.z, acc1);
                    acc1 = dot2(fu.w, wu.w, acc1);
                }
            }
            const float o = acc1 + bv;
            Yh[(size_t)(vox0 + wbase + v) * COUT + lane] = (_Float16)o;
            s += o; s2 += o * o;
        }
    }

    float* __restrict__ slab = slab0 + (size_t)(b & (NREP - 1)) * 128;
    sd[tid] = s;
    if (lane == 0) scnt[wv] = cnt;
    __syncthreads();
    if (tid < 64) atomicAdd(slab + tid, sd[tid] + sd[tid + 64] + sd[tid + 128] + sd[tid + 192]);
    __syncthreads();
    sd[tid] = s2;
    __syncthreads();
    if (tid < 64) atomicAdd(slab + 64 + tid, sd[tid] + sd[tid + 64] + sd[tid + 128] + sd[tid + 192]);
    if (tid == 0) atomicAdd(nacts + (b & (NREP - 1)), scnt[0] + scnt[1] + scnt[2] + scnt[3]);
}

// ---------------- finalize scale/shift from NREP slabs (stages 1,2) ---------
template <int C>
__global__ void k_finslab(const float* __restrict__ slab0,
                          const float* __restrict__ g,
                          const float* __restrict__ be,
                          float n, float* __restrict__ ss) {
    const int c = threadIdx.x;
    if (c >= C) return;
    float sm = 0.f, s2 = 0.f;
    for (int r = 0; r < NREP; ++r) {
        sm += slab0[r * 2 * C + c];
        s2 += slab0[r * 2 * C + C + c];
    }
    const float m  = sm / n;
    const float v  = s2 / n - m * m;
    const float sc = g[c] * rsqrtf(v + EPSf);
    ss[c]     = sc;
    ss[C + c] = be[c] - m * sc;
}

// ---------------- finalize scale/shift (stage 3, folds NREP replicas) -------
__global__ void k_finstats3(const float* __restrict__ slab0,
                            const int* __restrict__ nacts,
                            const float* __restrict__ g,
                            const float* __restrict__ be,
                            float* __restrict__ ss) {
    const int c = threadIdx.x;   // 64 threads
    if (c >= 64) return;
    float sm = 0.f, s2 = 0.f;
    int na = 0;
    for (int r = 0; r < NREP; ++r) {
        sm += slab0[r * 128 + c];
        s2 += slab0[r * 128 + 64 + c];
        na += nacts[r];
    }
    const float n  = (float)(na > 0 ? na : 1);
    const float m  = sm / n;
    const float v  = s2 / n - m * m;
    const float sc = g[c] * rsqrtf(v + EPSf);
    ss[c]      = sc;
    ss[64 + c] = be[c] - m * sc;
}

// --------- normalize (BN+ReLU): fp16 pre-norm in -> packed fp16 out ---------
template <int C>
__global__ __launch_bounds__(256) void k_norm16(const unsigned* __restrict__ Yp2,
                                                const float* __restrict__ ss,
                                                unsigned* __restrict__ Xo16, long n4) {
    const long t = (long)blockIdx.x * 256 + threadIdx.x;
    if (t >= n4) return;
    const uint2 y = ((const uint2*)Yp2)[t];
    const h2 lo = as_h2(y.x), hi = as_h2(y.y);
    const int ch = (int)((t * 4) % C);
    float ox = fmaxf(fmaf((float)lo.x, ss[ch],     ss[C + ch]),     0.f);
    float oy = fmaxf(fmaf((float)lo.y, ss[ch + 1], ss[C + ch + 1]), 0.f);
    float oz = fmaxf(fmaf((float)hi.x, ss[ch + 2], ss[C + ch + 2]), 0.f);
    float ow = fmaxf(fmaf((float)hi.y, ss[ch + 3], ss[C + ch + 3]), 0.f);
    uint2 o; o.x = hpk(ox, oy); o.y = hpk(oz, ow);
    ((uint2*)Xo16)[t] = o;
}

// ---------------- stage-3 normalize: fp16 in, fp32 out ----------------
__global__ __launch_bounds__(256) void k_norm3(const _Float16* __restrict__ Yh,
                                               const unsigned char* __restrict__ mask,
                                               const float* __restrict__ ss,
                                               float* __restrict__ out) {
    const long n4 = (long)M_ * COUT / 4;
    const long t = (long)blockIdx.x * 256 + threadIdx.x;
    if (t >= n4) return;
    const long vox = t >> 4;
    const int ch = (int)((t * 4) & 63);
    float4 o;
    if (mask[vox]) {
        const uint2 yu = *(const uint2*)(Yh + t * 4);
        const h2 ylo = as_h2(yu.x), yhi = as_h2(yu.y);
        o.x = fmaxf(fmaf((float)ylo.x, ss[ch],     ss[64 + ch]),     0.f);
        o.y = fmaxf(fmaf((float)ylo.y, ss[ch + 1], ss[64 + ch + 1]), 0.f);
        o.z = fmaxf(fmaf((float)yhi.x, ss[ch + 2], ss[64 + ch + 2]), 0.f);
        o.w = fmaxf(fmaf((float)yhi.y, ss[ch + 3], ss[64 + ch + 3]), 0.f);
    } else {
        o.x = o.y = o.z = o.w = 0.f;
    }
    ((float4*)out)[t] = o;
}

extern "C" void kernel_launch(void* const* d_in, const int* in_sizes, int n_in,
                              void* d_out, int out_size, void* d_ws, size_t ws_size,
                              hipStream_t stream) {
    const float* feats = (const float*)d_in[0];
    const int*   coords = (const int*)d_in[1];
    const float* W1 = (const float*)d_in[2];
    const float* b1 = (const float*)d_in[3];
    const float* g1 = (const float*)d_in[4];
    const float* be1 = (const float*)d_in[5];
    const float* W2 = (const float*)d_in[6];
    const float* b2 = (const float*)d_in[7];
    const float* g2 = (const float*)d_in[8];
    const float* be2 = (const float*)d_in[9];
    const float* W3 = (const float*)d_in[10];
    const float* b3 = (const float*)d_in[11];
    const float* g3 = (const float*)d_in[12];
    const float* be3 = (const float*)d_in[13];
    float* out = (float*)d_out;

    char* ws = (char*)d_ws;
    const size_t gridBytes = (size_t)B_ * D_ * H_ * W_ * 4;   // 16,777,216
    const size_t f16Bytes  = (size_t)N_ * CIN * 2;            //  4,800,000
    const size_t bufPBytes = (size_t)N_ * CMID * 2;           //  9,600,000
    const size_t YhBytes   = (size_t)M_ * COUT * 2;           // 67,108,864
    int*       grid   = (int*)ws;
    unsigned*  feat16 = (unsigned*)(ws + gridBytes);
    _Float16*  bufP   = (_Float16*)(ws + gridBytes + f16Bytes);             // pre-norm
    unsigned*  bufH   = (unsigned*)(ws + gridBytes + f16Bytes + bufPBytes); // normalized
    _Float16*  Yh     = (_Float16*)(ws + gridBytes + f16Bytes + 2 * bufPBytes);
    unsigned char* mask = (unsigned char*)(ws + gridBytes + f16Bytes + 2 * bufPBytes + YhBytes);
    float* stats = (float*)(ws + gridBytes + f16Bytes + 2 * bufPBytes + YhBytes + (size_t)M_);

    float* ss1   = stats;                 // 64
    float* ss2   = stats + 64;            // 64
    float* ss3   = stats + 128;           // 128
    float* slab1 = stats + 1024;                        // NREP*64
    float* slab2 = stats + 1024 + NREP * 64;            // NREP*64
    float* slab3 = stats + 1024 + NREP * 128;           // NREP*128
    int*   nacts = (int*)(stats + 1024 + NREP * 256);   // NREP ints
    uint4* Wh1 = (uint4*)(stats + 32768);               // 1728 uint4
    uint4* Wh2 = Wh1 + 1728;                            // 3456 uint4
    uint4* Wh3 = Wh2 + 3456;                            // 6912 uint4

    hipMemsetAsync(grid, 0xFF, gridBytes, stream);
    hipMemsetAsync(stats + 1024, 0, (NREP * 256 + NREP) * 4, stream); // slabs+nacts

    k_scatter<<<(N_ + 255) / 256, 256, 0, stream>>>(coords, grid);
    k_twisth<<<(12096 + 255) / 256, 256, 0, stream>>>(W1, W2, W3, Wh1, Wh2, Wh3);
    k_feat16<<<(N_ * CIN / 4 + 255) / 256, 256, 0, stream>>>(feats, feat16);

    const int nb_subm = N_ / 16;   // 9375 blocks: 4 waves x 4 points, exact
    k_subm<CIN><<<nb_subm, 256, 0, stream>>>(feat16, coords, grid, Wh1, b1, bufP, slab1);
    k_finslab<CMID><<<1, 64, 0, stream>>>(slab1, g1, be1, (float)N_, ss1);
    k_norm16<CMID><<<(N_ * CMID / 4 + 255) / 256, 256, 0, stream>>>(
        (const unsigned*)bufP, ss1, bufH, (long)N_ * CMID / 4);

    k_subm<CMID><<<nb_subm, 256, 0, stream>>>(bufH, coords, grid, Wh2, b2, bufP, slab2);
    k_finslab<CMID><<<1, 64, 0, stream>>>(slab2, g2, be2, (float)N_, ss2);
    k_norm16<CMID><<<(N_ * CMID / 4 + 255) / 256, 256, 0, stream>>>(
        (const unsigned*)bufP, ss2, bufH, (long)N_ * CMID / 4);

    k_down<<<NB_DOWN, 256, 0, stream>>>(bufH, grid, Wh3, b3, Yh, mask, slab3, nacts);
    k_finstats3<<<1, 64, 0, stream>>>(slab3, nacts, g3, be3, ss3);
    k_norm3<<<(M_ * COUT / 4) / 256, 256, 0, stream>>>(Yh, mask, ss3, out);
}

// Round 17
// 266.396 us; speedup vs baseline: 1.1778x; 1.1778x over previous
//
#include <hip/hip_runtime.h>

#define B_   2
#define D_   32
#define H_   256
#define W_   256
#define N_   150000
#define CIN  16
#define CMID 32
#define COUT 64
#define DO_  16
#define HO_  128
#define WO_  128
#define M_   (B_*DO_*HO_*WO_)   /* 524288 */
#define EPSf 1e-5f
#define NB_DOWN 8192             /* k_down blocks; %8==0, 64 voxels per block */
#define NREP 64                  /* stats slabs (atomic de-contention) */

typedef _Float16 h2 __attribute__((ext_vector_type(2)));
typedef _Float16 v8h __attribute__((ext_vector_type(8)));
typedef float    v4f __attribute__((ext_vector_type(4)));
union U4H8 { uint4 u; v8h h; };

__device__ inline h2 as_h2(unsigned u) { union { unsigned u; h2 h; } x; x.u = u; return x.h; }

#if defined(__has_builtin) && __has_builtin(__builtin_amdgcn_fdot2)
__device__ inline float dot2(unsigned f, unsigned w, float acc) {
    return __builtin_amdgcn_fdot2(as_h2(f), as_h2(w), acc, false);
}
#else
__device__ inline float dot2(unsigned f, unsigned w, float acc) {
    const h2 a = as_h2(f), b = as_h2(w);
    return fmaf((float)a.x, (float)b.x, fmaf((float)a.y, (float)b.y, acc));
}
#endif

// pack two floats into one dword of fp16 (RNE via _Float16 cast)
__device__ inline unsigned hpk(float a, float b) {
    union { _Float16 h[2]; unsigned u; } x;
    x.h[0] = (_Float16)a; x.h[1] = (_Float16)b; return x.u;
}

// ---------------- grid scatter ----------------
__global__ __launch_bounds__(256) void k_scatter(const int* __restrict__ coords,
                                                 int* __restrict__ grid) {
    int i = blockIdx.x * 256 + threadIdx.x;
    if (i >= N_) return;
    const int4 c = *(const int4*)(coords + 4 * (size_t)i);
    grid[((c.x * D_ + c.y) * H_ + c.z) * W_ + c.w] = i;
}

// ---------------- weight transpose+pack to fp16 ----------------
// Wh1/Wh2: dot2 layouts (unchanged). Wm3: MFMA B-fragment layout for
// mfma_f32_16x16x32_f16 -- lane l supplies B[k=8*(l>>4)+e][n=l&15];
// tile (w,ki) at Wm3[((w*27+ki)*64+lane)], n = co = 16w+(l&15).
__global__ __launch_bounds__(256) void k_twisth(const float* __restrict__ W1,
                                                const float* __restrict__ W2,
                                                const float* __restrict__ W3,
                                                uint4* __restrict__ Wh1,
                                                uint4* __restrict__ Wh2,
                                                uint4* __restrict__ Wm3) {
    const int t = blockIdx.x * 256 + threadIdx.x;
    if (t < 1728) {
        const int ki = t / 64, r = t % 64, half = r >> 5, sub = r & 31;
        const float* base = W1 + ki * 512 + (half * 8) * 32 + sub;
        uint4 o;
        o.x = hpk(base[0],   base[32]);
        o.y = hpk(base[64],  base[96]);
        o.z = hpk(base[128], base[160]);
        o.w = hpk(base[192], base[224]);
        Wh1[(ki * 2 + half) * 32 + sub] = o;
    } else if (t < 1728 + 3456) {
        const int u = t - 1728;
        const int ki = u / 128, r = u % 128, qh = r >> 5, sub = r & 31;
        const int half = qh >> 1, q = qh & 1;
        const float* base = W2 + ki * 1024 + (half * 16 + q * 8) * 32 + sub;
        uint4 o;
        o.x = hpk(base[0],   base[32]);
        o.y = hpk(base[64],  base[96]);
        o.z = hpk(base[128], base[160]);
        o.w = hpk(base[192], base[224]);
        Wh2[((ki * 2 + half) * 2 + q) * 32 + sub] = o;
    } else if (t < 1728 + 3456 + 6912) {
        const int u = t - 5184;          // 0..6911
        const int lane = u & 63;
        const int rest = u >> 6;         // 0..107 = w*27+ki
        const int w  = rest / 27;
        const int ki = rest % 27;
        const int k0 = (lane >> 4) * 8;
        const int co = w * 16 + (lane & 15);
        const float* base = W3 + ki * 2048 + co;
        uint4 o;
        o.x = hpk(base[(k0 + 0) * 64], base[(k0 + 1) * 64]);
        o.y = hpk(base[(k0 + 2) * 64], base[(k0 + 3) * 64]);
        o.z = hpk(base[(k0 + 4) * 64], base[(k0 + 5) * 64]);
        o.w = hpk(base[(k0 + 6) * 64], base[(k0 + 7) * 64]);
        Wm3[u] = o;
    }
}

// ---------------- feats fp32 -> fp16 pack ----------------
__global__ __launch_bounds__(256) void k_feat16(const float* __restrict__ F,
                                                unsigned* __restrict__ F16) {
    const int i = blockIdx.x * 256 + threadIdx.x;   // one float4 -> uint2
    if (i >= N_ * CIN / 4) return;
    const float4 v = ((const float4*)F)[i];
    uint2 o; o.x = hpk(v.x, v.y); o.y = hpk(v.z, v.w);
    ((uint2*)F16)[i] = o;
}

// ------- submanifold conv: 4 points/wave, branched 4-chain, fused stats -----
// (proven R14 config, untouched)
template <int CI>
__global__ __launch_bounds__(256) void k_subm(const unsigned* __restrict__ X16,
                                              const int* __restrict__ coords,
                                              const int* __restrict__ grid,
                                              const uint4* __restrict__ Wh,
                                              const float* __restrict__ bias,
                                              _Float16* __restrict__ Yp,
                                              float* __restrict__ slab0) {
    constexpr int NQ = CI / 16;   // uint4 loads per tap per lane (1 or 2)
    const int wid  = (blockIdx.x * 256 + threadIdx.x) >> 6;
    const int lane = threadIdx.x & 63;
    const int sub  = lane & 31;
    const int half = lane >> 5;
    const int i0   = wid * 4;

    int nidx01 = -1, nidx23 = -1;
    {
        const int4 cc = *(const int4*)(coords + 4 * (size_t)(i0 + half));
        if (sub < 27) {
            const int nz = cc.y + sub / 9 - 1;
            const int ny = cc.z + (sub / 3) % 3 - 1;
            const int nx = cc.w + sub % 3 - 1;
            if ((unsigned)nz < (unsigned)D_ && (unsigned)ny < (unsigned)H_ &&
                (unsigned)nx < (unsigned)W_)
                nidx01 = grid[((cc.x * D_ + nz) * H_ + ny) * W_ + nx];
        }
    }
    {
        const int4 cc = *(const int4*)(coords + 4 * (size_t)(i0 + 2 + half));
        if (sub < 27) {
            const int nz = cc.y + sub / 9 - 1;
            const int ny = cc.z + (sub / 3) % 3 - 1;
            const int nx = cc.w + sub % 3 - 1;
            if ((unsigned)nz < (unsigned)D_ && (unsigned)ny < (unsigned)H_ &&
                (unsigned)nx < (unsigned)W_)
                nidx23 = grid[((cc.x * D_ + nz) * H_ + ny) * W_ + nx];
        }
    }
    const unsigned long long a01 = __ballot(nidx01 >= 0);
    const unsigned long long a23 = __ballot(nidx23 >= 0);
    unsigned m0 = (unsigned)a01 & 0x7FFFFFFu;
    unsigned m1 = (unsigned)(a01 >> 32) & 0x7FFFFFFu;
    unsigned m2 = (unsigned)a23 & 0x7FFFFFFu;
    unsigned m3 = (unsigned)(a23 >> 32) & 0x7FFFFFFu;

    float4 ac0 = {0.f, 0.f, 0.f, 0.f}, ac1 = {0.f, 0.f, 0.f, 0.f};
    float4 ac2 = {0.f, 0.f, 0.f, 0.f}, ac3 = {0.f, 0.f, 0.f, 0.f};

    auto tap = [&](int ki, int ni, float4& ac) {
        const uint4* __restrict__ f =
            (const uint4*)(X16 + (size_t)ni * (CI / 2) + half * (CI / 4));
        const uint4* __restrict__ wb = Wh + ((size_t)(ki * 2 + half)) * NQ * 32 + sub;
#pragma unroll
        for (int q = 0; q < NQ; ++q) {
            const uint4 fu = f[q];
            const uint4 wu = wb[q * 32];
            ac.x = dot2(fu.x, wu.x, ac.x);
            ac.y = dot2(fu.y, wu.y, ac.y);
            ac.z = dot2(fu.z, wu.z, ac.z);
            ac.w = dot2(fu.w, wu.w, ac.w);
        }
    };

    while (m0 | m1 | m2 | m3) {
        if (m0) { const int ki = __builtin_ctz(m0); m0 &= m0 - 1;
                  tap(ki, __shfl(nidx01, ki, 64),      ac0); }
        if (m1) { const int ki = __builtin_ctz(m1); m1 &= m1 - 1;
                  tap(ki, __shfl(nidx01, ki + 32, 64), ac1); }
        if (m2) { const int ki = __builtin_ctz(m2); m2 &= m2 - 1;
                  tap(ki, __shfl(nidx23, ki, 64),      ac2); }
        if (m3) { const int ki = __builtin_ctz(m3); m3 &= m3 - 1;
                  tap(ki, __shfl(nidx23, ki + 32, 64), ac3); }
    }

    float s0 = (ac0.x + ac0.y) + (ac0.z + ac0.w);
    float s1 = (ac1.x + ac1.y) + (ac1.z + ac1.w);
    float s2v = (ac2.x + ac2.y) + (ac2.z + ac2.w);
    float s3 = (ac3.x + ac3.y) + (ac3.z + ac3.w);
    s0 += __shfl_xor(s0, 32, 64);
    s1 += __shfl_xor(s1, 32, 64);
    s2v += __shfl_xor(s2v, 32, 64);
    s3 += __shfl_xor(s3, 32, 64);
    const float bv  = bias[sub];
    const float o01 = (half ? s1 : s0) + bv;   // point i0+half
    const float o23 = (half ? s3 : s2v) + bv;  // point i0+2+half
    Yp[(size_t)(i0 + half) * 32 + sub]     = (_Float16)o01;
    Yp[(size_t)(i0 + 2 + half) * 32 + sub] = (_Float16)o23;

    // fused BN stats into NREP slabs
    __shared__ float sd[256];
    const int tid = threadIdx.x;
    float* __restrict__ slab = slab0 + (size_t)(blockIdx.x & (NREP - 1)) * 64;
    sd[tid] = o01 + o23;
    __syncthreads();
    if (tid < 32) {
        float t = 0.f;
#pragma unroll
        for (int k = 0; k < 8; ++k) t += sd[tid + 32 * k];
        atomicAdd(slab + tid, t);
    }
    __syncthreads();
    sd[tid] = o01 * o01 + o23 * o23;
    __syncthreads();
    if (tid < 32) {
        float t = 0.f;
#pragma unroll
        for (int k = 0; k < 8; ++k) t += sd[tid + 32 * k];
        atomicAdd(slab + 32 + tid, t);
    }
}

// ------ strided down conv: MFMA dense-over-ki, gather-A ---------------------
// Block = 64 voxels x 64 co. Wave w owns co tile [16w,16w+16) for all 64
// voxels (4 M-subtiles of 16). Per ki: B = prepacked fragment (1 uint4/lane),
// A = per-lane gathered feature chunk (voxel 16m+(l&15), k-chunk (l>>4)*8),
// zeroed by exec-mask when tap inactive; MFMA skipped when subtile empty.
__global__ __launch_bounds__(256) void k_down(const unsigned* __restrict__ X16,
                                              const int* __restrict__ grid,
                                              const uint4* __restrict__ Wm3,
                                              const float* __restrict__ bias,
                                              _Float16* __restrict__ Yh,
                                              unsigned char* __restrict__ mask,
                                              float* __restrict__ slab0,
                                              int* __restrict__ nacts) {
    const int b    = blockIdx.x;
    const int swz  = (b & 7) * (NB_DOWN / 8) + (b >> 3);
    const int tid  = threadIdx.x;
    const int wv   = tid >> 6;
    const int lane = tid & 63;
    const int col  = lane & 15;
    const int kg   = lane >> 4;

    const int vox0 = swz * 64;
    const int ox0  = vox0 & 127;      // 0 or 64
    int t0 = vox0 >> 7;
    const int oy = t0 & 127; t0 >>= 7;
    const int oz = t0 & 15;
    const int bb = t0 >> 4;

    __shared__ int   gl[9][132];
    __shared__ float sd[256];

    const int gx0 = 2 * ox0 - 1;
#pragma unroll
    for (int r = 0; r < 9; ++r) {
        const int z = 2 * oz - 1 + r / 3;
        const int y = 2 * oy - 1 + r % 3;
        if (tid < 132) {
            const int xo = tid;
            const int x  = gx0 + xo;
            int v = -1;
            if ((unsigned)z < (unsigned)D_ && (unsigned)y < (unsigned)H_ &&
                (unsigned)x < (unsigned)W_ && xo < 129)
                v = grid[((bb * D_ + z) * H_ + y) * W_ + x];
            gl[r][xo] = v;
        }
    }
    __syncthreads();

    const float bias_l = bias[wv * 16 + col];
    const uint4* __restrict__ wmrow = Wm3 + (size_t)(wv * 27) * 64 + lane;

    v4f acc0 = {0.f, 0.f, 0.f, 0.f}, acc1 = {0.f, 0.f, 0.f, 0.f};
    v4f acc2 = {0.f, 0.f, 0.f, 0.f}, acc3 = {0.f, 0.f, 0.f, 0.f};
    unsigned any0 = 0, any1 = 0, any2 = 0, any3 = 0;

    auto subtile = [&](int m, v4f& accv, unsigned& anyv, int row, int dxk, v8h wbh) {
        const int ni = gl[row][2 * (16 * m + col) + dxk];
        const unsigned long long blt = __ballot(ni >= 0);
        if (blt) {
            anyv |= (unsigned)blt & 0xFFFFu;
            U4H8 af; af.u.x = 0u; af.u.y = 0u; af.u.z = 0u; af.u.w = 0u;
            if (ni >= 0)
                af.u = *(const uint4*)(X16 + (size_t)ni * 16 + kg * 4);
            accv = __builtin_amdgcn_mfma_f32_16x16x32_f16(af.h, wbh, accv, 0, 0, 0);
        }
    };

    for (int ki = 0; ki < 27; ++ki) {
        const int row = ki / 3;       // dz*3+dy
        const int dxk = ki - row * 3;
        U4H8 wb; wb.u = wmrow[ki * 64];
        subtile(0, acc0, any0, row, dxk, wb.h);
        subtile(1, acc1, any1, row, dxk, wb.h);
        subtile(2, acc2, any2, row, dxk, wb.h);
        subtile(3, acc3, any3, row, dxk, wb.h);
    }

    float s = 0.f, s2 = 0.f;
    auto epi = [&](int m, const v4f& accv, unsigned anyv) {
#pragma unroll
        for (int r = 0; r < 4; ++r) {
            const int rowloc = kg * 4 + r;
            const float o = ((anyv >> rowloc) & 1u) ? (accv[r] + bias_l) : 0.f;
            Yh[(size_t)(vox0 + 16 * m + rowloc) * COUT + wv * 16 + col] = (_Float16)o;
            s += o; s2 += o * o;
        }
    };
    epi(0, acc0, any0); epi(1, acc1, any1); epi(2, acc2, any2); epi(3, acc3, any3);

    if (wv == 0 && lane < 16) {
        mask[vox0 +  0 + col] = (unsigned char)((any0 >> col) & 1u);
        mask[vox0 + 16 + col] = (unsigned char)((any1 >> col) & 1u);
        mask[vox0 + 32 + col] = (unsigned char)((any2 >> col) & 1u);
        mask[vox0 + 48 + col] = (unsigned char)((any3 >> col) & 1u);
    }

    // per-channel stats: thread's channel = 16*(tid>>6) + (tid&15); all 16 of
    // a thread's outputs share that channel. slab[c] = sum over the 4 kgroups.
    float* __restrict__ slab = slab0 + (size_t)(b & (NREP - 1)) * 128;
    sd[tid] = s;
    __syncthreads();
    if (tid < 64) {
        const int base = ((tid >> 4) << 6) + (tid & 15);
        atomicAdd(slab + tid, sd[base] + sd[base + 16] + sd[base + 32] + sd[base + 48]);
    }
    __syncthreads();
    sd[tid] = s2;
    __syncthreads();
    if (tid < 64) {
        const int base = ((tid >> 4) << 6) + (tid & 15);
        atomicAdd(slab + 64 + tid, sd[base] + sd[base + 16] + sd[base + 32] + sd[base + 48]);
    }
    if (tid == 0) {
        const int cnt = __popc(any0 & 0xFFFFu) + __popc(any1 & 0xFFFFu) +
                        __popc(any2 & 0xFFFFu) + __popc(any3 & 0xFFFFu);
        atomicAdd(nacts + (b & (NREP - 1)), cnt);
    }
}

// ---------------- finalize scale/shift from NREP slabs (stages 1,2) ---------
template <int C>
__global__ void k_finslab(const float* __restrict__ slab0,
                          const float* __restrict__ g,
                          const float* __restrict__ be,
                          float n, float* __restrict__ ss) {
    const int c = threadIdx.x;
    if (c >= C) return;
    float sm = 0.f, s2 = 0.f;
    for (int r = 0; r < NREP; ++r) {
        sm += slab0[r * 2 * C + c];
        s2 += slab0[r * 2 * C + C + c];
    }
    const float m  = sm / n;
    const float v  = s2 / n - m * m;
    const float sc = g[c] * rsqrtf(v + EPSf);
    ss[c]     = sc;
    ss[C + c] = be[c] - m * sc;
}

// ---------------- finalize scale/shift (stage 3, folds NREP replicas) -------
__global__ void k_finstats3(const float* __restrict__ slab0,
                            const int* __restrict__ nacts,
                            const float* __restrict__ g,
                            const float* __restrict__ be,
                            float* __restrict__ ss) {
    const int c = threadIdx.x;   // 64 threads
    if (c >= 64) return;
    float sm = 0.f, s2 = 0.f;
    int na = 0;
    for (int r = 0; r < NREP; ++r) {
        sm += slab0[r * 128 + c];
        s2 += slab0[r * 128 + 64 + c];
        na += nacts[r];
    }
    const float n  = (float)(na > 0 ? na : 1);
    const float m  = sm / n;
    const float v  = s2 / n - m * m;
    const float sc = g[c] * rsqrtf(v + EPSf);
    ss[c]      = sc;
    ss[64 + c] = be[c] - m * sc;
}

// --------- normalize (BN+ReLU): fp16 pre-norm in -> packed fp16 out ---------
template <int C>
__global__ __launch_bounds__(256) void k_norm16(const unsigned* __restrict__ Yp2,
                                                const float* __restrict__ ss,
                                                unsigned* __restrict__ Xo16, long n4) {
    const long t = (long)blockIdx.x * 256 + threadIdx.x;
    if (t >= n4) return;
    const uint2 y = ((const uint2*)Yp2)[t];
    const h2 lo = as_h2(y.x), hi = as_h2(y.y);
    const int ch = (int)((t * 4) % C);
    float ox = fmaxf(fmaf((float)lo.x, ss[ch],     ss[C + ch]),     0.f);
    float oy = fmaxf(fmaf((float)lo.y, ss[ch + 1], ss[C + ch + 1]), 0.f);
    float oz = fmaxf(fmaf((float)hi.x, ss[ch + 2], ss[C + ch + 2]), 0.f);
    float ow = fmaxf(fmaf((float)hi.y, ss[ch + 3], ss[C + ch + 3]), 0.f);
    uint2 o; o.x = hpk(ox, oy); o.y = hpk(oz, ow);
    ((uint2*)Xo16)[t] = o;
}

// ---------------- stage-3 normalize: fp16 in, fp32 out ----------------
__global__ __launch_bounds__(256) void k_norm3(const _Float16* __restrict__ Yh,
                                               const unsigned char* __restrict__ mask,
                                               const float* __restrict__ ss,
                                               float* __restrict__ out) {
    const long n4 = (long)M_ * COUT / 4;
    const long t = (long)blockIdx.x * 256 + threadIdx.x;
    if (t >= n4) return;
    const long vox = t >> 4;
    const int ch = (int)((t * 4) & 63);
    float4 o;
    if (mask[vox]) {
        const uint2 yu = *(const uint2*)(Yh + t * 4);
        const h2 ylo = as_h2(yu.x), yhi = as_h2(yu.y);
        o.x = fmaxf(fmaf((float)ylo.x, ss[ch],     ss[64 + ch]),     0.f);
        o.y = fmaxf(fmaf((float)ylo.y, ss[ch + 1], ss[64 + ch + 1]), 0.f);
        o.z = fmaxf(fmaf((float)yhi.x, ss[ch + 2], ss[64 + ch + 2]), 0.f);
        o.w = fmaxf(fmaf((float)yhi.y, ss[ch + 3], ss[64 + ch + 3]), 0.f);
    } else {
        o.x = o.y = o.z = o.w = 0.f;
    }
    ((float4*)out)[t] = o;
}

extern "C" void kernel_launch(void* const* d_in, const int* in_sizes, int n_in,
                              void* d_out, int out_size, void* d_ws, size_t ws_size,
                              hipStream_t stream) {
    const float* feats = (const float*)d_in[0];
    const int*   coords = (const int*)d_in[1];
    const float* W1 = (const float*)d_in[2];
    const float* b1 = (const float*)d_in[3];
    const float* g1 = (const float*)d_in[4];
    const float* be1 = (const float*)d_in[5];
    const float* W2 = (const float*)d_in[6];
    const float* b2 = (const float*)d_in[7];
    const float* g2 = (const float*)d_in[8];
    const float* be2 = (const float*)d_in[9];
    const float* W3 = (const float*)d_in[10];
    const float* b3 = (const float*)d_in[11];
    const float* g3 = (const float*)d_in[12];
    const float* be3 = (const float*)d_in[13];
    float* out = (float*)d_out;

    char* ws = (char*)d_ws;
    const size_t gridBytes = (size_t)B_ * D_ * H_ * W_ * 4;   // 16,777,216
    const size_t f16Bytes  = (size_t)N_ * CIN * 2;            //  4,800,000
    const size_t bufPBytes = (size_t)N_ * CMID * 2;           //  9,600,000
    const size_t YhBytes   = (size_t)M_ * COUT * 2;           // 67,108,864
    int*       grid   = (int*)ws;
    unsigned*  feat16 = (unsigned*)(ws + gridBytes);
    _Float16*  bufP   = (_Float16*)(ws + gridBytes + f16Bytes);             // pre-norm
    unsigned*  bufH   = (unsigned*)(ws + gridBytes + f16Bytes + bufPBytes); // normalized
    _Float16*  Yh     = (_Float16*)(ws + gridBytes + f16Bytes + 2 * bufPBytes);
    unsigned char* mask = (unsigned char*)(ws + gridBytes + f16Bytes + 2 * bufPBytes + YhBytes);
    float* stats = (float*)(ws + gridBytes + f16Bytes + 2 * bufPBytes + YhBytes + (size_t)M_);

    float* ss1   = stats;                 // 64
    float* ss2   = stats + 64;            // 64
    float* ss3   = stats + 128;           // 128
    float* slab1 = stats + 1024;                        // NREP*64
    float* slab2 = stats + 1024 + NREP * 64;            // NREP*64
    float* slab3 = stats + 1024 + NREP * 128;           // NREP*128
    int*   nacts = (int*)(stats + 1024 + NREP * 256);   // NREP ints
    uint4* Wh1 = (uint4*)(stats + 32768);               // 1728 uint4
    uint4* Wh2 = Wh1 + 1728;                            // 3456 uint4
    uint4* Wm3 = Wh2 + 3456;                            // 6912 uint4

    hipMemsetAsync(grid, 0xFF, gridBytes, stream);
    hipMemsetAsync(stats + 1024, 0, (NREP * 256 + NREP) * 4, stream); // slabs+nacts

    k_scatter<<<(N_ + 255) / 256, 256, 0, stream>>>(coords, grid);
    k_twisth<<<(12096 + 255) / 256, 256, 0, stream>>>(W1, W2, W3, Wh1, Wh2, Wm3);
    k_feat16<<<(N_ * CIN / 4 + 255) / 256, 256, 0, stream>>>(feats, feat16);

    const int nb_subm = N_ / 16;   // 9375 blocks: 4 waves x 4 points, exact
    k_subm<CIN><<<nb_subm, 256, 0, stream>>>(feat16, coords, grid, Wh1, b1, bufP, slab1);
    k_finslab<CMID><<<1, 64, 0, stream>>>(slab1, g1, be1, (float)N_, ss1);
    k_norm16<CMID><<<(N_ * CMID / 4 + 255) / 256, 256, 0, stream>>>(
        (const unsigned*)bufP, ss1, bufH, (long)N_ * CMID / 4);

    k_subm<CMID><<<nb_subm, 256, 0, stream>>>(bufH, coords, grid, Wh2, b2, bufP, slab2);
    k_finslab<CMID><<<1, 64, 0, stream>>>(slab2, g2, be2, (float)N_, ss2);
    k_norm16<CMID><<<(N_ * CMID / 4 + 255) / 256, 256, 0, stream>>>(
        (const unsigned*)bufP, ss2, bufH, (long)N_ * CMID / 4);

    k_down<<<NB_DOWN, 256, 0, stream>>>(bufH, grid, Wm3, b3, Yh, mask, slab3, nacts);
    k_finstats3<<<1, 64, 0, stream>>>(slab3, nacts, g3, be3, ss3);
    k_norm3<<<(M_ * COUT / 4) / 256, 256, 0, stream>>>(Yh, mask, ss3, out);
}